// Round 4
// baseline (11.491 us; speedup 1.0000x reference)
//
#include <hip/hip_runtime.h>

// Problem constants (match reference):
//   B=16, T=4096, D=256, W=512
//   out[b, w, 0:256]   = x_fwd[b, m_fwd[b,w],  :]   (m = idx if idx>=2 else 0)
//   out[b, w, 256:512] = x_bwd[b, m_back[b,w], :]
// Output: float32 (B, W, 2D) = 4,194,304 floats = 16 MiB.
//
// Layout: one thread handles ONE lane-position (float4) in BOTH halves of an
// output row. 64 lanes (one wave) = one full output row (128 float4).
//   - idx loads are wave-uniform broadcasts (one address per wave).
//   - gathered reads: 64 lanes x 16 B = contiguous 1 KiB row segment, coalesced.
//   - stores: two coalesced 1 KiB segments per wave. CACHED (not nontemporal):
//     on timed graph replays the 16 MiB output set is re-written every replay
//     and fits in L2 (2 MiB/XCD of 4 MiB) -> dirty lines re-dirty in place,
//     avoiding a forced 16 MiB HBM write-stream per replay. (R3 A/B: NT stores
//     pinned us at ~10.3 us.)

#define BB 16
#define TT 4096
#define DD 256
#define WW 512

typedef float f4 __attribute__((ext_vector_type(4)));

__global__ __launch_bounds__(256) void gather_concat_kernel(
    const f4* __restrict__ x_fwd,
    const f4* __restrict__ x_bwd,
    const int* __restrict__ idx_fwd,
    const int* __restrict__ idx_back,
    f4* __restrict__ out)
{
    const int i   = blockIdx.x * 256 + threadIdx.x;  // [0, B*W*64)
    const int d4  = i & 63;          // float4 position within a D-row (64 per row)
    const int row = i >> 6;          // b*W + w in [0, 8192)
    const int b   = row >> 9;        // W = 512

    int tf = idx_fwd[row];
    int tb = idx_back[row];
    if (tf < 2) tf = 0;              // reference: idx * (idx >= 2)
    if (tb < 2) tb = 0;

    const size_t base = (size_t)b * TT * 64;         // f4 offset of batch b
    const f4 vf = x_fwd[base + (size_t)tf * 64 + d4];
    const f4 vb = x_bwd[base + (size_t)tb * 64 + d4];

    f4* o = out + (size_t)row * 128 + d4;
    o[0]  = vf;
    o[64] = vb;
}

extern "C" void kernel_launch(void* const* d_in, const int* in_sizes, int n_in,
                              void* d_out, int out_size, void* d_ws, size_t ws_size,
                              hipStream_t stream) {
    const f4*  x_fwd    = (const f4*)d_in[0];
    const f4*  x_bwd    = (const f4*)d_in[1];
    const int* idx_fwd  = (const int*)d_in[2];
    const int* idx_back = (const int*)d_in[3];
    f4*        out      = (f4*)d_out;

    const int total_threads = BB * WW * 64;  // 524,288
    const int block = 256;
    const int grid = total_threads / block;  // 2048
    gather_concat_kernel<<<grid, block, 0, stream>>>(x_fwd, x_bwd, idx_fwd, idx_back, out);
}

// Round 5
// 10.186 us; speedup vs baseline: 1.1281x; 1.1281x over previous
//
#include <hip/hip_runtime.h>

// Problem constants (match reference):
//   B=16, T=4096, D=256, W=512
//   out[b, w, 0:256]   = x_fwd[b, m_fwd[b,w],  :]   (m = idx if idx>=2 else 0)
//   out[b, w, 256:512] = x_bwd[b, m_back[b,w], :]
// Output: float32 (B, W, 2D) = 4,194,304 floats = 16 MiB.
//
// R3/R4 A/B: NT stores (10.28us) beat cached stores (11.49us) -> keep NT.
// This round: 2 adjacent output rows per wave (4 float4 per thread):
//   - 4 independent gathers + 4 independent NT stores -> 2x MLP per wave
//   - adjacent rows share batch b and have adjacent indices -> int2 idx loads
//   - each wave writes 4 KiB CONTIGUOUS output (rows r0, r0+1)
//   - half the waves (4096) -> less dispatch ramp

#define BB 16
#define TT 4096
#define DD 256
#define WW 512

typedef float f4 __attribute__((ext_vector_type(4)));

__global__ __launch_bounds__(256) void gather_concat_kernel(
    const f4* __restrict__ x_fwd,
    const f4* __restrict__ x_bwd,
    const int* __restrict__ idx_fwd,
    const int* __restrict__ idx_back,
    f4* __restrict__ out)
{
    const int i  = blockIdx.x * 256 + threadIdx.x;   // [0, 262144)
    const int d4 = i & 63;            // float4 position within a D-row
    const int wv = i >> 6;            // wave id = row-pair id, [0, 4096)
    const int r0 = wv * 2;            // first row (even) ; r1 = r0+1 same batch
    const int b  = wv >> 8;           // r0 >> 9 == wv >> 8

    // adjacent indices -> one 8B load per array (wave-uniform broadcast)
    const int2 tf2 = ((const int2*)idx_fwd)[wv];
    const int2 tb2 = ((const int2*)idx_back)[wv];
    int tf0 = tf2.x, tf1 = tf2.y, tb0 = tb2.x, tb1 = tb2.y;
    if (tf0 < 2) tf0 = 0;             // reference: idx * (idx >= 2)
    if (tf1 < 2) tf1 = 0;
    if (tb0 < 2) tb0 = 0;
    if (tb1 < 2) tb1 = 0;

    const size_t base = (size_t)b * TT * 64;  // f4 offset of batch b
    // 4 independent gathers (coalesced 1 KiB per wave each)
    const f4 vf0 = x_fwd[base + (size_t)tf0 * 64 + d4];
    const f4 vb0 = x_bwd[base + (size_t)tb0 * 64 + d4];
    const f4 vf1 = x_fwd[base + (size_t)tf1 * 64 + d4];
    const f4 vb1 = x_bwd[base + (size_t)tb1 * 64 + d4];

    // wave writes 4 KiB contiguous: out[r0*128 .. r0*128+255]
    f4* o = out + (size_t)r0 * 128 + d4;
    __builtin_nontemporal_store(vf0, o);
    __builtin_nontemporal_store(vb0, o + 64);
    __builtin_nontemporal_store(vf1, o + 128);
    __builtin_nontemporal_store(vb1, o + 192);
}

extern "C" void kernel_launch(void* const* d_in, const int* in_sizes, int n_in,
                              void* d_out, int out_size, void* d_ws, size_t ws_size,
                              hipStream_t stream) {
    const f4*  x_fwd    = (const f4*)d_in[0];
    const f4*  x_bwd    = (const f4*)d_in[1];
    const int* idx_fwd  = (const int*)d_in[2];
    const int* idx_back = (const int*)d_in[3];
    f4*        out      = (f4*)d_out;

    const int total_threads = BB * WW * 32;  // 262,144 (2 rows per wave)
    const int block = 256;
    const int grid = total_threads / block;  // 1024
    gather_concat_kernel<<<grid, block, 0, stream>>>(x_fwd, x_bwd, idx_fwd, idx_back, out);
}